// Round 3
// baseline (294.340 us; speedup 1.0000x reference)
//
#include <hip/hip_runtime.h>

// Shapes: B=16, S=1024, E=64, H=8, d=8, INPUT_DIM=310
// local mask: |i-j|<=5 (11 keys); sparse mask: j%3==0 or i==j (342 keys + maybe diag)

#define INV_SQRT8 0.3535533905932738f

__device__ __forceinline__ float4 ld4(const float* p) { return *(const float4*)p; }

__device__ __forceinline__ float4 f4fma(float s, float4 w, float4 a) {
  a.x = fmaf(s, w.x, a.x); a.y = fmaf(s, w.y, a.y);
  a.z = fmaf(s, w.z, a.z); a.w = fmaf(s, w.w, a.w);
  return a;
}

// ---------------- GEMM: C[r, coff+n] = A[r,:K] . W[n,:K] + bias[n]
// BM=32, BN=64, 256 threads, 2x4 thread-tile. blockIdx.z selects between two
// (A,W,bias,C,coff) sets so independent GEMMs share one launch.
#define BM 32
#define BN 64
#define AST 68
#define WST 68

__global__ __launch_bounds__(256) void gemm_bias(
    const float* __restrict__ A0, const float* __restrict__ A1,
    const float* __restrict__ W0, const float* __restrict__ W1,
    const float* __restrict__ b0, const float* __restrict__ b1,
    float* __restrict__ C0, float* __restrict__ C1,
    int lda, int K, int ldc, int coff0, int coff1)
{
  __shared__ __align__(16) float As[BM * AST];
  __shared__ __align__(16) float Ws[64 * WST];

  const int z = blockIdx.z;
  const float* A = z ? A1 : A0;
  const float* W = z ? W1 : W0;
  const float* bias = z ? b1 : b0;
  float* C = z ? C1 : C0;
  const int coff = z ? coff1 : coff0;

  const int tid  = threadIdx.x;
  const int row0 = blockIdx.x * BM;
  const int col0 = blockIdx.y * BN;
  const int tcol = (tid & 15) * 4;
  const int trow = (tid >> 4) * 2;
  const bool vec = ((lda & 3) == 0) && ((K & 63) == 0);

  float4 acc[2];
  acc[0] = make_float4(0.f, 0.f, 0.f, 0.f);
  acc[1] = make_float4(0.f, 0.f, 0.f, 0.f);

  for (int k0 = 0; k0 < K; k0 += 64) {
    if (vec) {
      #pragma unroll
      for (int ii = 0; ii < 2; ii++) {
        int idx = tid + ii * 256;
        int r = idx >> 4, k4 = (idx & 15) * 4;
        *(float4*)&As[r * AST + k4] = ld4(&A[(size_t)(row0 + r) * lda + k0 + k4]);
      }
      #pragma unroll
      for (int ii = 0; ii < 4; ii++) {
        int idx = tid + ii * 256;
        int n = idx >> 4, k4 = (idx & 15) * 4;
        float4 w = ld4(&W[(size_t)(col0 + n) * K + k0 + k4]);
        Ws[(k4 + 0) * WST + n] = w.x;
        Ws[(k4 + 1) * WST + n] = w.y;
        Ws[(k4 + 2) * WST + n] = w.z;
        Ws[(k4 + 3) * WST + n] = w.w;
      }
    } else {
      for (int idx = tid; idx < BM * 64; idx += 256) {
        int r = idx >> 6, k = idx & 63, gk = k0 + k;
        As[r * AST + k] = (gk < K) ? A[(size_t)(row0 + r) * lda + gk] : 0.f;
      }
      for (int idx = tid; idx < BN * 64; idx += 256) {
        int n = idx >> 6, k = idx & 63, gk = k0 + k;
        Ws[k * WST + n] = (gk < K) ? W[(size_t)(col0 + n) * K + gk] : 0.f;
      }
    }
    __syncthreads();
    #pragma unroll
    for (int kk = 0; kk < 64; kk += 4) {
      float4 w0 = ld4(&Ws[(kk + 0) * WST + tcol]);
      float4 w1 = ld4(&Ws[(kk + 1) * WST + tcol]);
      float4 w2 = ld4(&Ws[(kk + 2) * WST + tcol]);
      float4 w3 = ld4(&Ws[(kk + 3) * WST + tcol]);
      #pragma unroll
      for (int i = 0; i < 2; i++) {
        float4 a = ld4(&As[(trow + i) * AST + kk]);
        acc[i] = f4fma(a.x, w0, acc[i]);
        acc[i] = f4fma(a.y, w1, acc[i]);
        acc[i] = f4fma(a.z, w2, acc[i]);
        acc[i] = f4fma(a.w, w3, acc[i]);
      }
    }
    __syncthreads();
  }
  float4 bv = ld4(&bias[col0 + tcol]);
  #pragma unroll
  for (int i = 0; i < 2; i++) {
    float4 o;
    o.x = acc[i].x + bv.x; o.y = acc[i].y + bv.y;
    o.z = acc[i].z + bv.z; o.w = acc[i].w + bv.w;
    *(float4*)&C[(size_t)(row0 + trow + i) * ldc + coff + col0 + tcol] = o;
  }
}

// ---------------- Local attention: thread per (b,i,h), 11-key window.
// qkv layout [B*S][192]: q=0..63, k=64..127, v=128..191; head h -> dims h*8..h*8+7
__global__ __launch_bounds__(256) void local_attn(
    const float* __restrict__ qkv, float* __restrict__ o)
{
  int t = blockIdx.x * 256 + threadIdx.x;   // B*S*H = 131072
  int h = t & 7;
  int i = (t >> 3) & 1023;
  int b = t >> 13;
  const float* base = qkv + (size_t)b * 1024 * 192;
  const float* qp = base + (size_t)i * 192 + h * 8;
  float4 q0 = ld4(qp), q1 = ld4(qp + 4);
  float l = 0.f;
  float4 o0 = make_float4(0.f, 0.f, 0.f, 0.f);
  float4 o1 = make_float4(0.f, 0.f, 0.f, 0.f);
  int jlo = i - 5; if (jlo < 0) jlo = 0;
  int jhi = i + 5; if (jhi > 1023) jhi = 1023;
  for (int j = jlo; j <= jhi; j++) {
    const float* kp = base + (size_t)j * 192 + 64 + h * 8;
    float4 k0 = ld4(kp), k1 = ld4(kp + 4);
    float s = q0.x * k0.x + q0.y * k0.y + q0.z * k0.z + q0.w * k0.w
            + q1.x * k1.x + q1.y * k1.y + q1.z * k1.z + q1.w * k1.w;
    float p = __expf(s * INV_SQRT8);
    l += p;
    float4 v0 = ld4(kp + 64), v1 = ld4(kp + 68);
    o0 = f4fma(p, v0, o0);
    o1 = f4fma(p, v1, o1);
  }
  float inv = 1.f / l;
  float* op = o + (size_t)(b * 1024 + i) * 64 + h * 8;
  float4 r0, r1;
  r0.x = o0.x * inv; r0.y = o0.y * inv; r0.z = o0.z * inv; r0.w = o0.w * inv;
  r1.x = o1.x * inv; r1.y = o1.y * inv; r1.z = o1.z * inv; r1.w = o1.w * inv;
  *(float4*)op = r0;
  *(float4*)(op + 4) = r1;
}

// ---------------- Global (sparse) attention: K/V addresses are wave-uniform
// (blockIdx + loop counter only) -> compiler emits s_load into SGPRs (scalar
// pipe, constant cache). Zero LDS, zero per-lane VMEM in the K-loop.
// Grid (16,8,4): 512 blocks, 1 query/thread, 2 blocks/CU.
#define NKEY 342
__global__ __launch_bounds__(256) void global_attn(
    const float* __restrict__ qkv, float* __restrict__ o)
{
  int b = blockIdx.x, h = blockIdx.y, qq = blockIdx.z;
  const float* base = qkv + (size_t)b * 1024 * 192;
  int i = qq * 256 + threadIdx.x;
  const float* qp = base + (size_t)i * 192 + h * 8;
  float4 q0 = ld4(qp), q1 = ld4(qp + 4);
  float l = 0.f;
  float4 o0 = make_float4(0.f, 0.f, 0.f, 0.f);
  float4 o1 = make_float4(0.f, 0.f, 0.f, 0.f);
  const float* kvb = base + 64 + h * 8;   // +j*192 -> K row; +64 more -> V row
  #pragma unroll 2
  for (int kk = 0; kk < NKEY; kk++) {
    const float* kp = kvb + (size_t)(kk * 3) * 192;   // wave-uniform address
    float k0 = kp[0], k1 = kp[1], k2 = kp[2], k3 = kp[3];
    float k4 = kp[4], k5 = kp[5], k6 = kp[6], k7 = kp[7];
    float v0 = kp[64], v1 = kp[65], v2 = kp[66], v3 = kp[67];
    float v4 = kp[68], v5 = kp[69], v6 = kp[70], v7 = kp[71];
    float s = q0.x*k0 + q0.y*k1 + q0.z*k2 + q0.w*k3
            + q1.x*k4 + q1.y*k5 + q1.z*k6 + q1.w*k7;
    float p = __expf(s * INV_SQRT8);
    l += p;
    o0.x = fmaf(p, v0, o0.x); o0.y = fmaf(p, v1, o0.y);
    o0.z = fmaf(p, v2, o0.z); o0.w = fmaf(p, v3, o0.w);
    o1.x = fmaf(p, v4, o1.x); o1.y = fmaf(p, v5, o1.y);
    o1.z = fmaf(p, v6, o1.z); o1.w = fmaf(p, v7, o1.w);
  }
  if (i % 3 != 0) {   // diagonal key not in the j%3==0 set (per-lane address)
    const float* kp = base + (size_t)i * 192 + 64 + h * 8;
    float4 k0 = ld4(kp), k1 = ld4(kp + 4);
    float s = q0.x*k0.x + q0.y*k0.y + q0.z*k0.z + q0.w*k0.w
            + q1.x*k1.x + q1.y*k1.y + q1.z*k1.z + q1.w*k1.w;
    float p = __expf(s * INV_SQRT8);
    l += p;
    float4 v0 = ld4(kp + 64), v1 = ld4(kp + 68);
    o0 = f4fma(p, v0, o0);
    o1 = f4fma(p, v1, o1);
  }
  float inv = 1.f / l;
  float* op = o + (size_t)(b * 1024 + i) * 64 + h * 8;
  float4 r0, r1;
  r0.x = o0.x * inv; r0.y = o0.y * inv; r0.z = o0.z * inv; r0.w = o0.w * inv;
  r1.x = o1.x * inv; r1.y = o1.y * inv; r1.z = o1.z * inv; r1.w = o1.w * inv;
  *(float4*)op = r0;
  *(float4*)(op + 4) = r1;
}

// ---------------- Pool scores: thread per row (64-thr blocks, grid 256)
__global__ __launch_bounds__(64) void score_kernel(
    const float* __restrict__ fused,
    const float* __restrict__ pw1, const float* __restrict__ pb1,
    const float* __restrict__ pw2, const float* __restrict__ pb2,
    float* __restrict__ scores)
{
  int r = blockIdx.x * 64 + threadIdx.x;   // 16384 rows
  const float* f = fused + (size_t)r * 64;
  float4 fr[16];
  #pragma unroll
  for (int e = 0; e < 16; e++) fr[e] = ld4(f + e * 4);
  float sc = pb2[0];
  #pragma unroll 4
  for (int j = 0; j < 32; j++) {
    const float* wr = pw1 + j * 64;
    float hj = pb1[j];
    #pragma unroll
    for (int e = 0; e < 16; e++) {
      float4 w = ld4(wr + e * 4);
      hj += fr[e].x * w.x + fr[e].y * w.y + fr[e].z * w.z + fr[e].w * w.w;
    }
    sc += tanhf(hj) * pw2[j];
  }
  scores[r] = sc;
}

// ---------------- Softmax over S (per b) + weighted sum -> out[b][64]
__global__ __launch_bounds__(1024) void pool_kernel(
    const float* __restrict__ fused, const float* __restrict__ scores,
    float* __restrict__ out)
{
  __shared__ float pbuf[1024];
  __shared__ float part[1024];
  __shared__ float red[20];
  int b = blockIdx.x, t = threadIdx.x;
  float sc = scores[b * 1024 + t];
  float m = sc;
  #pragma unroll
  for (int off = 32; off > 0; off >>= 1)
    m = fmaxf(m, __shfl_xor(m, off, 64));
  int wid = t >> 6, lane = t & 63;
  if (lane == 0) red[wid] = m;
  __syncthreads();
  if (t == 0) {
    float mm = red[0];
    for (int g = 1; g < 16; g++) mm = fmaxf(mm, red[g]);
    red[16] = mm;
  }
  __syncthreads();
  m = red[16];
  float p = __expf(sc - m);
  pbuf[t] = p;
  float ss = p;
  #pragma unroll
  for (int off = 32; off > 0; off >>= 1)
    ss += __shfl_xor(ss, off, 64);
  if (lane == 0) red[wid] = ss;
  __syncthreads();
  if (t == 0) {
    float s2 = 0.f;
    for (int g = 0; g < 16; g++) s2 += red[g];
    red[17] = 1.f / s2;
  }
  __syncthreads();
  float inv = red[17];
  int e = t & 63, g = t >> 6;
  float acc = 0.f;
  for (int s = g; s < 1024; s += 16)
    acc = fmaf(pbuf[s], fused[((size_t)b * 1024 + s) * 64 + e], acc);
  part[t] = acc;
  __syncthreads();
  if (t < 64) {
    float tot = 0.f;
    for (int g2 = 0; g2 < 16; g2++) tot += part[g2 * 64 + t];
    out[b * 64 + t] = tot * inv;
  }
}

extern "C" void kernel_launch(void* const* d_in, const int* in_sizes, int n_in,
                              void* d_out, int out_size, void* d_ws, size_t ws_size,
                              hipStream_t stream)
{
  const float* x          = (const float*)d_in[0];
  const float* proj_w     = (const float*)d_in[1];
  const float* proj_b     = (const float*)d_in[2];
  const float* loc_in_w   = (const float*)d_in[3];
  const float* loc_in_b   = (const float*)d_in[4];
  const float* loc_out_w  = (const float*)d_in[5];
  const float* loc_out_b  = (const float*)d_in[6];
  const float* glob_in_w  = (const float*)d_in[7];
  const float* glob_in_b  = (const float*)d_in[8];
  const float* glob_out_w = (const float*)d_in[9];
  const float* glob_out_b = (const float*)d_in[10];
  const float* fusion_w   = (const float*)d_in[11];
  const float* fusion_b   = (const float*)d_in[12];
  const float* pw1        = (const float*)d_in[13];
  const float* pb1        = (const float*)d_in[14];
  const float* pw2        = (const float*)d_in[15];
  const float* pb2        = (const float*)d_in[16];

  float* ws     = (float*)d_ws;
  float* xp     = ws;                 // [16384,64]  (reused as FUSED later)
  float* qkv_l  = ws + 1048576;       // [16384,192]
  float* qkv_g  = ws + 4194304;       // [16384,192]
  float* o_l    = ws + 7340032;       // [16384,64]
  float* o_g    = ws + 8388608;       // [16384,64]
  float* cat    = ws + 9437184;       // [16384,128]
  float* scores = ws + 11534336;      // [16384]
  float* fused  = xp;
  float* out    = (float*)d_out;

  dim3 blk(256);
  // xp = x @ proj_w^T + proj_b      (M=16384,K=310,N=64), grid 512
  gemm_bias<<<dim3(512, 1, 1), blk, 0, stream>>>(
      x, x, proj_w, proj_w, proj_b, proj_b, xp, xp, 310, 310, 64, 0, 0);
  // qkv (both branches merged): (512,3,2)
  gemm_bias<<<dim3(512, 3, 2), blk, 0, stream>>>(
      xp, xp, loc_in_w, glob_in_w, loc_in_b, glob_in_b, qkv_l, qkv_g,
      64, 64, 192, 0, 0);
  // attention branches
  local_attn<<<512, blk, 0, stream>>>(qkv_l, o_l);
  global_attn<<<dim3(16, 8, 4), blk, 0, stream>>>(qkv_g, o_g);
  // out-projections merged into concat buffer: (512,1,2)
  gemm_bias<<<dim3(512, 1, 2), blk, 0, stream>>>(
      o_l, o_g, loc_out_w, glob_out_w, loc_out_b, glob_out_b, cat, cat,
      64, 64, 128, 0, 64);
  // fused = cat @ fusion_w^T + fusion_b   (K=128,N=64), grid 512
  gemm_bias<<<dim3(512, 1, 1), blk, 0, stream>>>(
      cat, cat, fusion_w, fusion_w, fusion_b, fusion_b, fused, fused,
      128, 128, 64, 0, 0);
  // pooling
  score_kernel<<<256, dim3(64), 0, stream>>>(fused, pw1, pb1, pw2, pb2, scores);
  pool_kernel<<<16, dim3(1024), 0, stream>>>(fused, scores, out);
}